// Round 14
// baseline (185.162 us; speedup 1.0000x reference)
//
#include <hip/hip_runtime.h>

// Sinkhorn (dustbin-augmented), MFMA fp8 edition v14.
//
// Goal: 2 blocks/CU (all 512 batches resident). Enablers:
//  * no LDS score tile at all -- fragments built directly from global scores
//    (LDS ~2 KB total), and
//  * fp8 e4m3 MFMA operands (mfma_f32_16x16x32_fp8_fp8): fragments are 32
//    VGPRs, letting the kernel fit the 64-reg budget for 8 waves/EU.
//
// State (same recursions as the verified f16 versions v8..v13):
//   EU_i  = 1/(sum_j es_ij*EV_j + A*evd)        es = 2^{s*log2e}
//   eud_s = Cs/(sum_j EV_j + evd),  Cs = 2^8/A, A = 2^{alpha*log2e}
//   EV_j  = 1/(sum_i es_ij*EU_i + A*eud_s)
//   evd'  = Cs/(sum_i EU_i + eud_s)
//   Z core = (s*log2e + log2 EU + log2 EV)*ln2  (dustbins use alpha2)
// fp8 carries only the matvec operands (es, 16*EU, 16*EV -- the dustbin term
// bounds EU,EV so 16*x sits in e4m3's normal range). All scalar math f32;
// EU/EV published as f16 for the epilogue logs; the epilogue direct term
// re-reads exact f32 scores (L3-warm), so fp8 error enters Z only via u,v.
//
// Operand maps: wave w, lane l = l15 + 16g, chunk s (K-slice 32):
//   esA[s] byte j = es[16w+l15][32s+8g+j]     (A row strip)
//   esB[s] byte j = es[32s+8g+j][16w+l15]     (B col strip)
//   EV8/EU8 fragment byte j = val[32s+8g+j]   (replicated operand)
// Any error in the assumed lane->k map cancels (A and B share it).
// C/D: col=lane&15, row=(lane>>4)*4+reg (HW-measured, dtype-independent).

typedef float floatx4 __attribute__((ext_vector_type(4)));
typedef unsigned int uint2v __attribute__((ext_vector_type(2)));
typedef _Float16 half8v __attribute__((ext_vector_type(8)));

constexpr float L2E = 1.4426950408889634f;
constexpr float LN2 = 0.6931471805599453f;

__device__ __forceinline__ float flog2(float x) { return __builtin_amdgcn_logf(x); }
__device__ __forceinline__ float fexp2(float x) { return __builtin_amdgcn_exp2f(x); }

__device__ __forceinline__ float rcp_nr(float d) {
    float r = __builtin_amdgcn_rcpf(d);
    return r * fmaf(-d, r, 2.0f);
}

template <int CTRL>
__device__ __forceinline__ float dpp_add(float x) {
    int y = __builtin_amdgcn_update_dpp(0, __builtin_bit_cast(int, x), CTRL, 0xF, 0xF, true);
    return x + __builtin_bit_cast(float, y);
}
__device__ __forceinline__ float reduce16(float x) {
    x = dpp_add<0xB1>(x);    // xor 1
    x = dpp_add<0x4E>(x);    // xor 2
    x = dpp_add<0x124>(x);   // row_ror:4
    x = dpp_add<0x128>(x);   // row_ror:8
    return x;
}
__device__ __forceinline__ float xor16_add(float x) {
    int y = __builtin_amdgcn_ds_swizzle(__builtin_bit_cast(int, x), 0x401F);
    return x + __builtin_bit_cast(float, y);
}

// f32 -> OCP e4m3fn (x >= 0), round-half-up, clamp 448, subnormals exact-ish.
__device__ __forceinline__ unsigned f32_to_e4m3(float x) {
    if (!(x > 0.0f)) return 0u;
    if (x < 0.015625f) {                       // < 2^-6: subnormal (m * 2^-9)
        int mi = (int)fmaf(x, 512.0f, 0.5f);   // 0..8 (8 == 2^-6 == 0x08)
        return (unsigned)mi;
    }
    unsigned u = __builtin_bit_cast(unsigned, x);
    unsigned r = u + 0x80000u;                 // round mantissa at bit 20
    int e2 = (int)((r >> 23) & 255u) - 127;
    if (e2 > 8) return 0x7Eu;                  // clamp to 448
    unsigned b = (unsigned)(((e2 + 7) << 3) | ((r >> 20) & 7u));
    if (b >= 0x7Fu) b = 0x7Eu;                 // avoid NaN encoding
    return b;
}

__device__ __forceinline__ long pack8_e4m3(const float* v) {
    unsigned lo = 0, hi = 0;
    #pragma unroll
    for (int j = 0; j < 4; ++j) lo |= f32_to_e4m3(v[j]) << (8 * j);
    #pragma unroll
    for (int j = 0; j < 4; ++j) hi |= f32_to_e4m3(v[j + 4]) << (8 * j);
    uint2v p; p.x = lo; p.y = hi;
    return __builtin_bit_cast(long, p);
}

__global__ __launch_bounds__(1024)
__attribute__((amdgpu_waves_per_eu(8, 8)))
void sinkhorn_kernel(const float* __restrict__ scores,
                     const float* __restrict__ alpha_p,
                     const int* __restrict__ iters_p,
                     float* __restrict__ out)
{
    const int bat = blockIdx.x;
    const int t   = threadIdx.x;
    const int w   = t >> 6;         // wave 0..15
    const int l   = t & 63;
    const int g   = (t >> 4) & 3;   // k-group within wave
    const int l15 = t & 15;

    const float alpha2 = alpha_p[0] * L2E;
    const float A  = fexp2(alpha2);
    const float Cs = fexp2(8.0f - alpha2);   // 2^8 / A
    const int iters = iters_p[0];

    __shared__ __align__(16) unsigned char EV8a[288];   // fp8(16*EV)
    __shared__ __align__(16) unsigned char EU8a[288];   // fp8(16*EU)
    __shared__ __align__(16) unsigned short EUa[288];   // f16 EU (true scale)
    __shared__ __align__(16) unsigned short EVa[288];   // f16 EV
    __shared__ __align__(16) float wsU[16];
    __shared__ __align__(16) float wsV[16];

    const float* S = scores + ((size_t)bat << 16);
    const int row = (w << 4) + l15;          // this lane's matrix row / col id

    // ---- build fragments straight from global (no LDS tile) ----
    long esA[8], esB[8];
    {
        const float* rowp = S + (row << 8) + (g << 3);
        #pragma unroll
        for (int s = 0; s < 8; ++s) {
            const float4 x0 = *reinterpret_cast<const float4*>(rowp + (s << 5));
            const float4 x1 = *reinterpret_cast<const float4*>(rowp + (s << 5) + 4);
            float v[8] = {fexp2(x0.x * L2E), fexp2(x0.y * L2E),
                          fexp2(x0.z * L2E), fexp2(x0.w * L2E),
                          fexp2(x1.x * L2E), fexp2(x1.y * L2E),
                          fexp2(x1.z * L2E), fexp2(x1.w * L2E)};
            esA[s] = pack8_e4m3(v);
            asm volatile("" : "+v"(esA[s]));  // pin: no remat/spill games
        }
        #pragma unroll
        for (int s = 0; s < 8; ++s) {
            const float* cp = S + (((s << 5) + (g << 3)) << 8) + row;
            float v[8];
            #pragma unroll
            for (int j = 0; j < 8; ++j) v[j] = fexp2(cp[j << 8] * L2E);
            esB[s] = pack8_e4m3(v);
            asm volatile("" : "+v"(esB[s]));
        }
    }

    // ---- init: EV = 1  ->  EV8 = 16 (0x58), f16 1.0, wave sums 16 ----
    if (t < 64)  reinterpret_cast<unsigned*>(EV8a)[t] = 0x58585858u;
    if (t < 256) EVa[t] = 0x3C00;
    if (t < 16)  wsV[t] = 16.0f;
    __syncthreads();

    float evd = 1.0f, eud_s = 1.0f;

    for (int it = 0; it < iters; ++it) {
        // ---- scalars: eud_s from Sum(EV) + evd (all threads, redundant) ----
        float sv = evd;
        {
            const floatx4* wv = reinterpret_cast<const floatx4*>(wsV);
            floatx4 s0 = wv[0], s1 = wv[1], s2 = wv[2], s3 = wv[3];
            floatx4 ss = (s0 + s1) + (s2 + s3);
            sv += (ss[0] + ss[1]) + (ss[2] + ss[3]);
        }
        eud_s = Cs * rcp_nr(sv);
        const float tdu16 = 16.0f * A * eud_s;
        const float tdv16 = 16.0f * A * evd;

        // ---- p-phase: acc = 16 * (sum_k es[m][k]*EV[k])  (2x4 chains) ----
        floatx4 acc0 = {0.f, 0.f, 0.f, 0.f}, acc1 = {0.f, 0.f, 0.f, 0.f};
        #pragma unroll
        for (int s = 0; s < 4; ++s) {
            const long b0 = *reinterpret_cast<const long*>(&EV8a[((2*s) << 5) + (g << 3)]);
            const long b1 = *reinterpret_cast<const long*>(&EV8a[((2*s+1) << 5) + (g << 3)]);
            acc0 = __builtin_amdgcn_mfma_f32_16x16x32_fp8_fp8(esA[2*s],   b0, acc0, 0, 0, 0);
            acc1 = __builtin_amdgcn_mfma_f32_16x16x32_fp8_fp8(esA[2*s+1], b1, acc1, 0, 0, 0);
        }
        const floatx4 acc = acc0 + acc1;

        const float E0 = 16.0f * rcp_nr(acc[0] + tdv16);
        const float E1 = 16.0f * rcp_nr(acc[1] + tdv16);
        const float E2 = 16.0f * rcp_nr(acc[2] + tdv16);
        const float E3 = 16.0f * rcp_nr(acc[3] + tdv16);
        if (l15 < 4) {  // rows 16w + 4g + l15
            const float lo  = (l15 & 1) ? E1 : E0;
            const float hi  = (l15 & 1) ? E3 : E2;
            const float val = (l15 & 2) ? hi : lo;
            const int idx = (w << 4) + (g << 2) + l15;
            EUa[idx]  = __builtin_bit_cast(unsigned short, (_Float16)val);
            EU8a[idx] = (unsigned char)f32_to_e4m3(val * 16.0f);
        }
        float sU = (E0 + E1) + (E2 + E3);
        sU = xor16_add(sU);
        sU += __shfl_xor(sU, 32, 64);
        if (l == 0) wsU[w] = sU;
        __syncthreads();

        // ---- scalars: evd' from Sum(EU) + eud_s ----
        float su = eud_s;
        {
            const floatx4* wu = reinterpret_cast<const floatx4*>(wsU);
            floatx4 s0 = wu[0], s1 = wu[1], s2 = wu[2], s3 = wu[3];
            floatx4 ss = (s0 + s1) + (s2 + s3);
            su += (ss[0] + ss[1]) + (ss[2] + ss[3]);
        }
        evd = Cs * rcp_nr(su);

        // ---- q-phase: acc2 = 16 * (sum_k EU[k]*es[k][n])  (2x4 chains) ----
        floatx4 q0 = {0.f, 0.f, 0.f, 0.f}, q1 = {0.f, 0.f, 0.f, 0.f};
        #pragma unroll
        for (int s = 0; s < 4; ++s) {
            const long a0 = *reinterpret_cast<const long*>(&EU8a[((2*s) << 5) + (g << 3)]);
            const long a1 = *reinterpret_cast<const long*>(&EU8a[((2*s+1) << 5) + (g << 3)]);
            q0 = __builtin_amdgcn_mfma_f32_16x16x32_fp8_fp8(a0, esB[2*s],   q0, 0, 0, 0);
            q1 = __builtin_amdgcn_mfma_f32_16x16x32_fp8_fp8(a1, esB[2*s+1], q1, 0, 0, 0);
        }
        const floatx4 acc2 = q0 + q1;

        const float EVv = 16.0f * rcp_nr(acc2[0] + tdu16);   // col 16w+l15
        if (l < 16) {
            EVa[(w << 4) + l]  = __builtin_bit_cast(unsigned short, (_Float16)EVv);
            EV8a[(w << 4) + l] = (unsigned char)f32_to_e4m3(EVv * 16.0f);
        }
        float sV = reduce16(EVv);
        if (l == 0) wsV[w] = sV;
        __syncthreads();
    }

    // ---- epilogue: direct term from exact f32 scores (L3-warm re-read) ----
    const float Ud = flog2(eud_s);
    const float Vd = flog2(evd);
    const float Up_l = flog2((float)__builtin_bit_cast(_Float16, EUa[(w << 4) + l15]));
    const size_t ob = (size_t)bat * 66049;  // 257*257
    float* rp = out + ob + (size_t)row * 257;
    const float* rowp = S + (row << 8) + (g << 3);

    #pragma unroll
    for (int s = 0; s < 8; ++s) {
        const float4 x0 = *reinterpret_cast<const float4*>(rowp + (s << 5));
        const float4 x1 = *reinterpret_cast<const float4*>(rowp + (s << 5) + 4);
        const half8v vh = *reinterpret_cast<const half8v*>(&EVa[(s << 5) + (g << 3)]);
        const int c0 = (s << 5) + (g << 3);
        const float xs[8] = {x0.x, x0.y, x0.z, x0.w, x1.x, x1.y, x1.z, x1.w};
        #pragma unroll
        for (int j = 0; j < 8; ++j)
            rp[c0 + j] = (xs[j] * L2E + Up_l + flog2((float)vh[j])) * LN2;
    }
    if (l < 16) rp[256] = (alpha2 + Up_l + Vd) * LN2;   // dustbin column
    if (t < 257) {
        const float vp = (t < 256)
            ? flog2((float)__builtin_bit_cast(_Float16, EVa[t])) : Vd;
        out[ob + 65792 + t] = (alpha2 + Ud + vp) * LN2;
    }
}

extern "C" void kernel_launch(void* const* d_in, const int* in_sizes, int n_in,
                              void* d_out, int out_size, void* d_ws, size_t ws_size,
                              hipStream_t stream)
{
    const float* scores = (const float*)d_in[0];
    const float* alpha  = (const float*)d_in[1];
    const int*   iters  = (const int*)d_in[2];
    float* out = (float*)d_out;
    const int B = in_sizes[0] >> 16;
    hipLaunchKernelGGL(sinkhorn_kernel, dim3(B), dim3(1024), 0, stream,
                       scores, alpha, iters, out);
}

// Round 15
// 164.285 us; speedup vs baseline: 1.1271x; 1.1271x over previous
//
#include <hip/hip_runtime.h>

// Sinkhorn (dustbin-augmented), fp8 MFMA edition v15.
// 512-thread blocks (8 waves), TWO blocks/CU co-resident (waves_per_eu(4,4),
// 128-reg budget -- the budget at which v9 provably held 64 pinned fragment
// regs). Each wave owns two 16-row and two 16-col strips. No LDS score tile
// (LDS ~2.3 KB); fragments built straight from global once; epilogue decodes
// the fp8 esA fragments in-register (no global re-read).
//
// State (validated v8..v14; fp8 operand path validated v14 at absmax 0.0625):
//   EU_i  = 1/(sum_j es_ij*EV_j + A*evd)        es = 2^{s*log2e}
//   eud_s = Cs/(sum_j EV_j + evd),  Cs = 2^8/A, A = 2^{alpha*log2e}
//   EV_j  = 1/(sum_i es_ij*EU_i + A*eud_s)
//   evd'  = Cs/(sum_i EU_i + eud_s)
//   Z core = (log2 es + log2 EU + log2 EV)*ln2  (dustbins use alpha2)
// fp8 carries es, 16*EU, 16*EV (scale-16 keeps e4m3 normal range; accs are
// 16x true, recovered via tdv16/tdu16 -- identical to v14).
//
// Maps: wave w (0..7), lane l = l15 + 16g, strip r in {0,1}:
//   row_r / col_r = 16*(w + 8r) + l15
//   esA[r][s] byte j = es[row_r][32s+8g+j]     (A row strip)
//   esB[r][s] byte j = es[32s+8g+j][col_r]     (B col strip)
//   EV8/EU8 fragment chunk s byte j = val[32s+8g+j] (replicated operand)
// C/D: col=lane&15, row=(lane>>4)*4+reg (HW-measured, dtype-independent).

typedef float floatx4 __attribute__((ext_vector_type(4)));
typedef unsigned int uint2v __attribute__((ext_vector_type(2)));
typedef _Float16 half8v __attribute__((ext_vector_type(8)));

constexpr float L2E = 1.4426950408889634f;
constexpr float LN2 = 0.6931471805599453f;

__device__ __forceinline__ float flog2(float x) { return __builtin_amdgcn_logf(x); }
__device__ __forceinline__ float fexp2(float x) { return __builtin_amdgcn_exp2f(x); }

__device__ __forceinline__ float rcp_nr(float d) {
    float r = __builtin_amdgcn_rcpf(d);
    return r * fmaf(-d, r, 2.0f);
}

template <int CTRL>
__device__ __forceinline__ float dpp_add(float x) {
    int y = __builtin_amdgcn_update_dpp(0, __builtin_bit_cast(int, x), CTRL, 0xF, 0xF, true);
    return x + __builtin_bit_cast(float, y);
}
__device__ __forceinline__ float reduce16(float x) {
    x = dpp_add<0xB1>(x);    // xor 1
    x = dpp_add<0x4E>(x);    // xor 2
    x = dpp_add<0x124>(x);   // row_ror:4
    x = dpp_add<0x128>(x);   // row_ror:8
    return x;
}
__device__ __forceinline__ float xor16_add(float x) {
    int y = __builtin_amdgcn_ds_swizzle(__builtin_bit_cast(int, x), 0x401F);
    return x + __builtin_bit_cast(float, y);
}

// f32 -> OCP e4m3fn (x >= 0), round-half-up, clamp 448 (validated v14).
__device__ __forceinline__ unsigned f32_to_e4m3(float x) {
    if (!(x > 0.0f)) return 0u;
    if (x < 0.015625f) {
        int mi = (int)fmaf(x, 512.0f, 0.5f);
        return (unsigned)mi;
    }
    unsigned u = __builtin_bit_cast(unsigned, x);
    unsigned r = u + 0x80000u;
    int e2 = (int)((r >> 23) & 255u) - 127;
    if (e2 > 8) return 0x7Eu;
    unsigned b = (unsigned)(((e2 + 7) << 3) | ((r >> 20) & 7u));
    if (b >= 0x7Fu) b = 0x7Eu;
    return b;
}
__device__ __forceinline__ long pack8_e4m3(const float* v) {
    unsigned lo = 0, hi = 0;
    #pragma unroll
    for (int j = 0; j < 4; ++j) lo |= f32_to_e4m3(v[j]) << (8 * j);
    #pragma unroll
    for (int j = 0; j < 4; ++j) hi |= f32_to_e4m3(v[j + 4]) << (8 * j);
    uint2v p; p.x = lo; p.y = hi;
    return __builtin_bit_cast(long, p);
}
// e4m3fn byte -> f32 (non-negative)
__device__ __forceinline__ float dec_e4m3(unsigned b) {
    unsigned e = (b >> 3) & 15u, m = b & 7u;
    if (e == 0) return (float)m * 0.001953125f;      // m * 2^-9
    return __builtin_bit_cast(float, ((e + 120u) << 23) | (m << 20));
}

__global__ __launch_bounds__(512)
__attribute__((amdgpu_waves_per_eu(4, 4)))
void sinkhorn_kernel(const float* __restrict__ scores,
                     const float* __restrict__ alpha_p,
                     const int* __restrict__ iters_p,
                     float* __restrict__ out)
{
    const int bat = blockIdx.x;
    const int t   = threadIdx.x;
    const int w   = t >> 6;         // wave 0..7
    const int l   = t & 63;
    const int g   = (t >> 4) & 3;   // k-group within wave
    const int l15 = t & 15;

    const float alpha2 = alpha_p[0] * L2E;
    const float A  = fexp2(alpha2);
    const float Cs = fexp2(8.0f - alpha2);   // 2^8 / A
    const int iters = iters_p[0];

    __shared__ __align__(16) unsigned char  EV8a[288];  // fp8(16*EV)
    __shared__ __align__(16) unsigned char  EU8a[288];  // fp8(16*EU)
    __shared__ __align__(16) unsigned short EUa[288];   // f16 EU
    __shared__ __align__(16) unsigned short EVa[288];   // f16 EV
    __shared__ __align__(16) float wsU[8];
    __shared__ __align__(16) float wsV[8];

    const float* S = scores + ((size_t)bat << 16);
    const int r0 = (w << 4) + l15;           // strip-0 row/col id
    const int r1 = r0 + 128;                 // strip-1 row/col id

    // ---- fragments straight from global (no LDS tile), asm-pinned ----
    long esA[2][8], esB[2][8];
    #pragma unroll
    for (int r = 0; r < 2; ++r) {
        const int row = r ? r1 : r0;
        const float* rowp = S + (row << 8) + (g << 3);
        #pragma unroll
        for (int s = 0; s < 8; ++s) {
            const float4 x0 = *reinterpret_cast<const float4*>(rowp + (s << 5));
            const float4 x1 = *reinterpret_cast<const float4*>(rowp + (s << 5) + 4);
            float v[8] = {fexp2(x0.x * L2E), fexp2(x0.y * L2E),
                          fexp2(x0.z * L2E), fexp2(x0.w * L2E),
                          fexp2(x1.x * L2E), fexp2(x1.y * L2E),
                          fexp2(x1.z * L2E), fexp2(x1.w * L2E)};
            esA[r][s] = pack8_e4m3(v);
            asm volatile("" : "+v"(esA[r][s]));
        }
    }
    #pragma unroll
    for (int r = 0; r < 2; ++r) {
        const int col = r ? r1 : r0;
        #pragma unroll
        for (int s = 0; s < 8; ++s) {
            const float* cp = S + (((s << 5) + (g << 3)) << 8) + col;
            float v[8];
            #pragma unroll
            for (int j = 0; j < 8; ++j) v[j] = fexp2(cp[j << 8] * L2E);
            esB[r][s] = pack8_e4m3(v);
            asm volatile("" : "+v"(esB[r][s]));
        }
    }

    // ---- init: EV = 1 -> fp8(16)=0x58, f16 1.0, per-wave col sum 32 ----
    if (t < 64)  reinterpret_cast<unsigned*>(EV8a)[t] = 0x58585858u;
    if (t < 256) EVa[t] = 0x3C00;
    if (t < 8)   wsV[t] = 32.0f;
    __syncthreads();

    float evd = 1.0f, eud_s = 1.0f;

    for (int it = 0; it < iters; ++it) {
        // ---- scalars: eud_s from Sum(EV) + evd (all threads, redundant) ----
        float sv = evd;
        {
            const floatx4* wv = reinterpret_cast<const floatx4*>(wsV);
            const floatx4 ss = wv[0] + wv[1];
            sv += (ss[0] + ss[1]) + (ss[2] + ss[3]);
        }
        eud_s = Cs * rcp_nr(sv);
        const float tdu16 = 16.0f * A * eud_s;
        const float tdv16 = 16.0f * A * evd;

        // ---- p-phase: both strips, 2 chains each ----
        floatx4 c00 = {0,0,0,0}, c01 = {0,0,0,0}, c10 = {0,0,0,0}, c11 = {0,0,0,0};
        #pragma unroll
        for (int s = 0; s < 4; ++s) {
            const long b0 = *reinterpret_cast<const long*>(&EV8a[((2*s) << 5) + (g << 3)]);
            const long b1 = *reinterpret_cast<const long*>(&EV8a[((2*s+1) << 5) + (g << 3)]);
            c00 = __builtin_amdgcn_mfma_f32_16x16x32_fp8_fp8(esA[0][2*s],   b0, c00, 0, 0, 0);
            c01 = __builtin_amdgcn_mfma_f32_16x16x32_fp8_fp8(esA[0][2*s+1], b1, c01, 0, 0, 0);
            c10 = __builtin_amdgcn_mfma_f32_16x16x32_fp8_fp8(esA[1][2*s],   b0, c10, 0, 0, 0);
            c11 = __builtin_amdgcn_mfma_f32_16x16x32_fp8_fp8(esA[1][2*s+1], b1, c11, 0, 0, 0);
        }
        const floatx4 ap0 = c00 + c01;
        const floatx4 ap1 = c10 + c11;

        float E0[4], E1[4];
        #pragma unroll
        for (int i = 0; i < 4; ++i) {
            E0[i] = 16.0f * rcp_nr(ap0[i] + tdv16);
            E1[i] = 16.0f * rcp_nr(ap1[i] + tdv16);
        }
        if (l15 < 4) {  // publish rows 16(w+8r) + 4g + l15 from reg l15
            const float v0 = (l15 & 2) ? ((l15 & 1) ? E0[3] : E0[2])
                                       : ((l15 & 1) ? E0[1] : E0[0]);
            const float v1 = (l15 & 2) ? ((l15 & 1) ? E1[3] : E1[2])
                                       : ((l15 & 1) ? E1[1] : E1[0]);
            const int i0 = (w << 4) + (g << 2) + l15;
            EUa[i0]        = __builtin_bit_cast(unsigned short, (_Float16)v0);
            EU8a[i0]       = (unsigned char)f32_to_e4m3(v0 * 16.0f);
            EUa[i0 + 128]  = __builtin_bit_cast(unsigned short, (_Float16)v1);
            EU8a[i0 + 128] = (unsigned char)f32_to_e4m3(v1 * 16.0f);
        }
        float sU = ((E0[0] + E0[1]) + (E0[2] + E0[3]))
                 + ((E1[0] + E1[1]) + (E1[2] + E1[3]));
        sU = xor16_add(sU);
        sU += __shfl_xor(sU, 32, 64);
        if (l == 0) wsU[w] = sU;
        __syncthreads();

        // ---- scalars: evd' from Sum(EU) + eud_s ----
        float su = eud_s;
        {
            const floatx4* wu = reinterpret_cast<const floatx4*>(wsU);
            const floatx4 ss = wu[0] + wu[1];
            su += (ss[0] + ss[1]) + (ss[2] + ss[3]);
        }
        evd = Cs * rcp_nr(su);

        // ---- q-phase: both strips ----
        floatx4 q00 = {0,0,0,0}, q01 = {0,0,0,0}, q10 = {0,0,0,0}, q11 = {0,0,0,0};
        #pragma unroll
        for (int s = 0; s < 4; ++s) {
            const long a0 = *reinterpret_cast<const long*>(&EU8a[((2*s) << 5) + (g << 3)]);
            const long a1 = *reinterpret_cast<const long*>(&EU8a[((2*s+1) << 5) + (g << 3)]);
            q00 = __builtin_amdgcn_mfma_f32_16x16x32_fp8_fp8(a0, esB[0][2*s],   q00, 0, 0, 0);
            q01 = __builtin_amdgcn_mfma_f32_16x16x32_fp8_fp8(a1, esB[0][2*s+1], q01, 0, 0, 0);
            q10 = __builtin_amdgcn_mfma_f32_16x16x32_fp8_fp8(a0, esB[1][2*s],   q10, 0, 0, 0);
            q11 = __builtin_amdgcn_mfma_f32_16x16x32_fp8_fp8(a1, esB[1][2*s+1], q11, 0, 0, 0);
        }
        const floatx4 aq0 = q00 + q01;
        const floatx4 aq1 = q10 + q11;

        const float EVv0 = 16.0f * rcp_nr(aq0[0] + tdu16);   // col r0 (m-replicated)
        const float EVv1 = 16.0f * rcp_nr(aq1[0] + tdu16);   // col r1
        if (l < 16) {
            EVa[(w << 4) + l]        = __builtin_bit_cast(unsigned short, (_Float16)EVv0);
            EV8a[(w << 4) + l]       = (unsigned char)f32_to_e4m3(EVv0 * 16.0f);
            EVa[(w << 4) + l + 128]  = __builtin_bit_cast(unsigned short, (_Float16)EVv1);
            EV8a[(w << 4) + l + 128] = (unsigned char)f32_to_e4m3(EVv1 * 16.0f);
        }
        float sV = reduce16(EVv0) + reduce16(EVv1);
        if (l == 0) wsV[w] = sV;
        __syncthreads();
    }

    // ---- epilogue: s' decoded from fp8 esA fragments (no global re-read) ----
    const float Ud = flog2(eud_s);
    const float Vd = flog2(evd);
    const float Up0 = flog2((float)__builtin_bit_cast(_Float16, EUa[r0]));
    const float Up1 = flog2((float)__builtin_bit_cast(_Float16, EUa[r1]));
    const size_t ob = (size_t)bat * 66049;  // 257*257
    float* rp0 = out + ob + (size_t)r0 * 257;
    float* rp1 = out + ob + (size_t)r1 * 257;

    #pragma unroll
    for (int s = 0; s < 8; ++s) {
        const uint2v pa0 = __builtin_bit_cast(uint2v, esA[0][s]);
        const uint2v pa1 = __builtin_bit_cast(uint2v, esA[1][s]);
        const half8v vh = *reinterpret_cast<const half8v*>(&EVa[(s << 5) + (g << 3)]);
        const int c0 = (s << 5) + (g << 3);
        #pragma unroll
        for (int j = 0; j < 8; ++j) {
            const float vlog = flog2((float)vh[j]);
            const unsigned b0 = (pa0[j >> 2] >> ((j & 3) * 8)) & 255u;
            const unsigned b1 = (pa1[j >> 2] >> ((j & 3) * 8)) & 255u;
            rp0[c0 + j] = (flog2(dec_e4m3(b0)) + Up0 + vlog) * LN2;
            rp1[c0 + j] = (flog2(dec_e4m3(b1)) + Up1 + vlog) * LN2;
        }
    }
    if (l < 16) {   // dustbin column for both strips' rows
        rp0[256] = (alpha2 + Up0 + Vd) * LN2;
        rp1[256] = (alpha2 + Up1 + Vd) * LN2;
    }
    if (t < 257) {  // dustbin row incl. corner
        const float vp = (t < 256)
            ? flog2((float)__builtin_bit_cast(_Float16, EVa[t])) : Vd;
        out[ob + 65792 + t] = (alpha2 + Ud + vp) * LN2;
    }
}

extern "C" void kernel_launch(void* const* d_in, const int* in_sizes, int n_in,
                              void* d_out, int out_size, void* d_ws, size_t ws_size,
                              hipStream_t stream)
{
    const float* scores = (const float*)d_in[0];
    const float* alpha  = (const float*)d_in[1];
    const int*   iters  = (const int*)d_in[2];
    float* out = (float*)d_out;
    const int B = in_sizes[0] >> 16;
    hipLaunchKernelGGL(sinkhorn_kernel, dim3(B), dim3(512), 0, stream,
                       scores, alpha, iters, out);
}